// Round 9
// baseline (56.869 us; speedup 1.0000x reference)
//
#include <hip/hip_runtime.h>
#include <math.h>

#define BLOCK 256
#define CN    2048          // refs staged in LDS per block
#define NT    (CN / 32)     // 64 col-tiles per chunk

typedef _Float16 f16;
typedef _Float16 f16x8 __attribute__((ext_vector_type(8)));
typedef float f32x16 __attribute__((ext_vector_type(16)));
typedef unsigned long long u64;

union HU { f16 h; unsigned short u; };
static __device__ __forceinline__ unsigned short h16(float x) {
    HU v; v.h = (f16)x; return v.u;
}
static __device__ __forceinline__ u64 shflxor32_u64(u64 v, int m) {
    unsigned lo = (unsigned)v, hi = (unsigned)(v >> 32);
    lo = __shfl_xor(lo, m, 32);
    hi = __shfl_xor(hi, m, 32);
    return ((u64)hi << 32) | lo;
}

// MFMA chamfer scan. One mfma_f32_32x32x16_f16 evaluates 32 queries x 32 refs:
//   e = d^2 + 64 - ||q||^2  =  A(f16 q) . B(f16 -2r)  +  C(f32 w=||r||^2+64)
// A: lanes 0-31 elems 0-2 = (qx,qy,qz), all else 0; B: lanes 0-31 elems 0-2 =
// (-2rx,-2ry,-2rz) for col=lane&31, all else 0. With K-content only in
// k=0..2, this placement is invariant to the (l>>5)*8+j vs (l>>5)*4+j
// k-mapping ambiguity. C/D layout (verified): col=lane&31,
// row=(reg&3)+8*(reg>>2)+4*(lane>>5) -> each lane's 16 accs are 16 rows of
// one col: 16 independent min-chains over col-tiles.
// Key: (bits(e) & ~127) | tile_j  (tile_j 0..127, 7 bits; e>0 so u32 order =
// float order; masking granularity ~1e-3 in d^2, same scale as f16 noise; the
// reduce kernel recomputes the winning distance EXACTLY from raw f32 coords).
// Wave epilogue: butterfly-min across the 32 cols per half-wave, then one
// lane per half issues 16 atomicMin(u64) with key64=(key<<5)|col, whose low
// 12 bits are the global ref index. Ties pick lowest ref index (jnp.argmin
// first-occurrence). atomicMin is commutative/idempotent => deterministic.
__global__ __launch_bounds__(BLOCK, 4)
void chamfer_mfma_kernel(const float* __restrict__ pc_src,
                         const float* __restrict__ pc_dst,
                         u64* __restrict__ part,   // [B*M] dir0 then [B*N] dir1
                         int M, int N, int B, int Zc0) {
    __shared__ uint4 lds_ref[CN + 1];   // 16B per ref: f16(-2x,-2y,-2z),0-pad; [CN]=zero stub
    __shared__ float lds_w[CN];         // ||r||^2 + 64 (f32)

    const int rg = blockIdx.x;          // row-group of 128 queries
    const int b  = blockIdx.y;
    const int z  = blockIdx.z;
    const int dir = (z >= Zc0) ? 1 : 0;
    const int chunk = dir ? (z - Zc0) : z;

    const int NQ = dir ? N : M;
    const int NR = dir ? M : N;
    const float* pcq = dir ? pc_dst : pc_src;
    const float* pcr = dir ? pc_src : pc_dst;
    u64* pp = part + (dir ? (size_t)B * M : (size_t)0) + (size_t)b * NQ;

    const int tid = threadIdx.x;
    const int lane = tid & 63;
    const int wid = tid >> 6;           // wave 0..3
    const int n0 = chunk * CN;

    // ---- stage refs (coalesced f32 loads; convert once per block) ----
    const float* rb = pcr + (size_t)b * 3 * NR + n0;
    for (int i = tid; i < CN; i += BLOCK) {
        const float rx = rb[i], ry = rb[NR + i], rz = rb[2 * NR + i];
        const unsigned u0 = (unsigned)h16(-2.0f * rx) | ((unsigned)h16(-2.0f * ry) << 16);
        const unsigned u1 = (unsigned)h16(-2.0f * rz);
        lds_ref[i] = make_uint4(u0, u1, 0u, 0u);
        lds_w[i] = fmaf(rx, rx, fmaf(ry, ry, rz * rz)) + 64.0f;
    }
    if (tid == 0) lds_ref[CN] = make_uint4(0u, 0u, 0u, 0u);

    // ---- A fragment: this wave's 32 query rows ----
    const int row0 = rg * 128 + wid * 32;
    f16x8 afrag = {0, 0, 0, 0, 0, 0, 0, 0};
    if (lane < 32) {
        const float* qb = pcq + (size_t)b * 3 * NQ + row0 + lane;
        afrag[0] = (f16)qb[0];
        afrag[1] = (f16)qb[NQ];
        afrag[2] = (f16)qb[2 * NQ];
    }

    __syncthreads();

    const int col = lane & 31;
    const bool lo = (lane < 32);
    const uint4* bptr = lo ? &lds_ref[col] : &lds_ref[CN];  // hi lanes: zero stub
    const int bstep = lo ? 32 : 0;

    unsigned kmin[16];
#pragma unroll
    for (int r = 0; r < 16; ++r) kmin[r] = 0xFFFFFFFFu;

    const unsigned emask = ~127u;
    const unsigned tj0 = (unsigned)(chunk * NT);

    for (int t = 0; t < NT; ++t) {
        const f16x8 bfrag = *(const f16x8*)bptr;   // ds_read_b128
        bptr += bstep;
        const float wval = lds_w[t * 32 + col];
        f32x16 acc;
#pragma unroll
        for (int r = 0; r < 16; ++r) acc[r] = wval;   // C-init = w[col] (f32)
        acc = __builtin_amdgcn_mfma_f32_32x32x16_f16(afrag, bfrag, acc, 0, 0, 0);
        const unsigned tj = tj0 + (unsigned)t;
#pragma unroll
        for (int r = 0; r < 16; ++r) {
            const unsigned key = (__float_as_uint(acc[r]) & emask) | tj;
            kmin[r] = key < kmin[r] ? key : kmin[r];
        }
    }

    // ---- per-row min across the 32 cols (butterfly within each half) ----
    const int rhalf = (lane >> 5) * 4;
#pragma unroll
    for (int r = 0; r < 16; ++r) {
        u64 k64 = ((u64)kmin[r] << 5) | (unsigned)col;
        for (int m2 = 1; m2 <= 16; m2 <<= 1) {
            const u64 o = shflxor32_u64(k64, m2);
            k64 = (o < k64) ? o : k64;
        }
        if (col == 0) {
            const int row = (r & 3) + 8 * (r >> 2) + rhalf;
            atomicMin(&pp[row0 + row], k64);
        }
    }
}

// Epilogue: one thread per query (both directions concatenated in part).
// Low 12 bits of key64 = global argmin ref index; recompute the winning
// distance EXACTLY from raw f32 coords, weight by sigma, block-reduce,
// one atomicAdd per block.
__global__ void chamfer_reduce_kernel(const float* __restrict__ pc_src,
                                      const float* __restrict__ pc_dst,
                                      const float* __restrict__ sig_src,
                                      const float* __restrict__ sig_dst,
                                      const u64* __restrict__ part,
                                      float* __restrict__ out,
                                      int M, int N, int B) {
    __shared__ float red[BLOCK];
    const int TT = blockIdx.x * BLOCK + threadIdx.x;
    const int dir = (TT >= B * M);           // uniform per block (B*M % 256 == 0)
    const int t = dir ? TT - B * M : TT;     // t = b*NQ + q

    const int NQ = dir ? N : M;
    const int NR = dir ? M : N;
    const float* pcq  = dir ? pc_dst : pc_src;
    const float* pcr  = dir ? pc_src : pc_dst;
    const float* sigq = dir ? sig_dst : sig_src;
    const float* sigr = dir ? sig_src : sig_dst;
    const float scale = 1.0f / (float)(B * NQ);

    const int b = t / NQ;
    const int q = t - b * NQ;

    const int gidx = (int)((unsigned)part[TT] & (unsigned)(NR - 1));

    const float* qbase = pcq + (size_t)b * 3 * NQ;
    const float* rbase = pcr + (size_t)b * 3 * NR;
    const float dx = qbase[q]          - rbase[gidx];
    const float dy = qbase[NQ + q]     - rbase[NR + gidx];
    const float dz = qbase[2 * NQ + q] - rbase[2 * NR + gidx];
    const float dist = sqrtf(fmaf(dx, dx, fmaf(dy, dy, dz * dz)));

    const float s = 0.5f * (sigq[t] + sigr[(size_t)b * NR + gidx]);
    red[threadIdx.x] = dist * s * scale;
    __syncthreads();

    for (int w = BLOCK / 2; w > 0; w >>= 1) {
        if (threadIdx.x < w) red[threadIdx.x] += red[threadIdx.x + w];
        __syncthreads();
    }
    if (threadIdx.x == 0) atomicAdd(out, red[0]);
}

extern "C" void kernel_launch(void* const* d_in, const int* in_sizes, int n_in,
                              void* d_out, int out_size, void* d_ws, size_t ws_size,
                              hipStream_t stream) {
    const float* pc_src  = (const float*)d_in[0];   // [B,3,M]
    const float* pc_dst  = (const float*)d_in[1];   // [B,3,N]
    const float* sig_src = (const float*)d_in[2];   // [B,M]
    const float* sig_dst = (const float*)d_in[3];   // [B,N]
    float* out = (float*)d_out;

    const int B = 8;
    const int M = in_sizes[2] / B;   // 4096
    const int N = in_sizes[3] / B;   // 4096

    u64* part = (u64*)d_ws;          // B*M dir0 keys, then B*N dir1 keys
    const size_t partBytes = (size_t)B * (M + N) * sizeof(u64);   // 512 KiB

    hipMemsetAsync(part, 0xFF, partBytes, stream);   // u64 max sentinels
    hipMemsetAsync(d_out, 0, sizeof(float), stream);

    const int Zc0 = N / CN;          // chunks for dir0 (refs = dst)
    const int Zc1 = M / CN;          // chunks for dir1 (refs = src)

    {   // MFMA min-scan, both directions: grid (4096/128, 8, 4) = 1024 blocks
        dim3 grid(M / 128, B, Zc0 + Zc1);
        chamfer_mfma_kernel<<<grid, BLOCK, 0, stream>>>(
            pc_src, pc_dst, part, M, N, B, Zc0);
    }
    {   // epilogue over all queries of both directions
        dim3 rgrid((B * (M + N)) / BLOCK);
        chamfer_reduce_kernel<<<rgrid, BLOCK, 0, stream>>>(
            pc_src, pc_dst, sig_src, sig_dst, part, out, M, N, B);
    }
}